// Round 12
// baseline (848.038 us; speedup 1.0000x reference)
//
#include <hip/hip_runtime.h>
#include <math.h>

#define NF 128      // feature/hidden dim (F == H == 128)
#define NU 64       // uints per bf16 row (NF/2)
#define TROWS 32    // fused-kernel tile rows
#define ARS 68      // As row stride in u32 (64 + 4 pad)
#define CRS 132     // Cs row stride in floats (128 + 4 pad)

typedef unsigned int  u32;
typedef unsigned short u16;
typedef u32 b4 __attribute__((ext_vector_type(2)));     // 4 bf16 (8B)
typedef short bf16x8 __attribute__((ext_vector_type(8)));  // MFMA A/B frag (16B)
typedef float f32x4 __attribute__((ext_vector_type(4)));   // MFMA C/D frag

__device__ inline u16 f2bf(float f) {               // RNE float->bf16
    u32 u = __float_as_uint(f);
    return (u16)((u + 0x7fffu + ((u >> 16) & 1u)) >> 16);
}
__device__ inline u32 pack2(float a, float b) {     // ch2k=lo, ch2k+1=hi
    return (u32)f2bf(a) | ((u32)f2bf(b) << 16);
}
__device__ inline float bflo(u32 u) { return __uint_as_float(u << 16); }
__device__ inline float bfhi(u32 u) { return __uint_as_float(u & 0xffff0000u); }

// ---------- setup kernels ----------

__global__ void k_deg(const int* __restrict__ ei, int* cnt, int E) {
    int e = blockIdx.x * blockDim.x + threadIdx.x;
    if (e < E) atomicAdd(&cnt[ei[E + e]], 1);   // dst row; cnt = deg w/o self-loop
}

// Exclusive scan over PADDED counts vpad = roundup(cnt+1, 4); item n has v=0 so
// offs[n] lands automatically. Also emits dinv = rsqrt(real deg).
__global__ void k_scan1(const int* __restrict__ cnt, float* dinv,
                        int* offs, int* bsum, int n) {
    __shared__ int s[256];
    int t = threadIdx.x;
    int i = blockIdx.x * 256 + t;
    int v = 0;
    if (i < n) {
        int real = cnt[i] + 1;          // +1 self-loop
        dinv[i] = 1.0f / sqrtf((float)real);
        v = (real + 3) & ~3;            // pad row to multiple of 4
    }
    s[t] = v;
    for (int d = 1; d < 256; d <<= 1) {
        __syncthreads();
        int add = (t >= d) ? s[t - d] : 0;
        __syncthreads();
        s[t] += add;
    }
    __syncthreads();
    if (i <= n) offs[i] = s[t] - v;          // exclusive
    if (t == 255) bsum[blockIdx.x] = s[255]; // block total
}

__global__ void k_scan2(int* bsum, int nb) {
    __shared__ int s[512];
    int t = threadIdx.x;
    int v = (t < nb) ? bsum[t] : 0;
    s[t] = v;
    for (int d = 1; d < 512; d <<= 1) {
        __syncthreads();
        int add = (t >= d) ? s[t - d] : 0;
        __syncthreads();
        s[t] += add;
    }
    __syncthreads();
    if (t < nb) bsum[t] = s[t] - v;         // exclusive
}

__global__ void k_scan3(int* offs, const int* __restrict__ bsum, int* cursor, int n) {
    int i = blockIdx.x * 256 + threadIdx.x;
    if (i <= n) {
        int o = offs[i] + bsum[blockIdx.x];
        offs[i] = o;
        cursor[i] = o;
    }
}

// One prep kernel:
//  (a) q0[row] = bf16(dinv[row] * x[row])  (row n -> zeros; sentinel row)
//  (b) scatter real edges into padded dst-sorted CSR via atomic cursor,
//      self-loop + sentinel padding at row end
//  (c) t < 8192: pre-swizzled bf16 B-fragments of the 4 weight matrices.
__global__ void k_prep(const int* __restrict__ ei, const float* __restrict__ x,
                       const float* __restrict__ dinv, const int* __restrict__ cnt,
                       const int* __restrict__ offs, int* cursor, int* srcS,
                       u32* __restrict__ q,
                       const float* __restrict__ W0, const float* __restrict__ W1,
                       const float* __restrict__ W2, const float* __restrict__ W3,
                       u32* __restrict__ wt, int E, int n) {
    int t = blockIdx.x * blockDim.x + threadIdx.x;
    int totalu4 = (n + 1) * (NU / 4);     // 16 uint4 per row
    if (t < totalu4) {
        int row = t >> 4;
        uint4 o = make_uint4(0, 0, 0, 0);
        if (row < n) {
            int cbase = (t & 15) << 3;    // 8 channels per uint4
            const float* xr = x + (size_t)row * NF + cbase;
            float4 f0 = *(const float4*)(xr);
            float4 f1 = *(const float4*)(xr + 4);
            float d = dinv[row];
            o.x = pack2(f0.x * d, f0.y * d);
            o.y = pack2(f0.z * d, f0.w * d);
            o.z = pack2(f1.x * d, f1.y * d);
            o.w = pack2(f1.z * d, f1.w * d);
        }
        ((uint4*)q)[t] = o;
    }
    if (t < E) {
        int s = ei[t], d = ei[E + t];
        int p = atomicAdd(&cursor[d], 1);
        srcS[p] = s;
    } else if (t < E + n) {
        int i = t - E;
        int base = offs[i] + cnt[i];      // after the cnt[i] real edges
        srcS[base] = i;                   // self-loop
        int end = offs[i + 1];
        for (int k = base + 1; k < end; ++k) srcS[k] = n;   // sentinel padding
    }
    if (t < 4 * 2048) {
        int layer = t >> 11;
        int rem = t & 2047;               // = (nt*4+ks)*64 + lane
        int lane = rem & 63;
        int ks = (rem >> 6) & 3;
        int nt = rem >> 8;
        const float* W = layer == 0 ? W0 : layer == 1 ? W1 : layer == 2 ? W2 : W3;
        int nn = nt * 16 + (lane & 15);
        int k0 = ks * 32 + (lane >> 4) * 8;
        uint4 o;
        o.x = pack2(W[(k0 + 0) * NF + nn], W[(k0 + 1) * NF + nn]);
        o.y = pack2(W[(k0 + 2) * NF + nn], W[(k0 + 3) * NF + nn]);
        o.z = pack2(W[(k0 + 4) * NF + nn], W[(k0 + 5) * NF + nn]);
        o.w = pack2(W[(k0 + 6) * NF + nn], W[(k0 + 7) * NF + nn]);
        ((uint4*)wt)[t] = o;
    }
}

// ---------- fused layer: bf16 gather-sum -> bf16 LDS tile -> MFMA GEMM -> epilogue ----------
// hin: bf16 q = dinv*h (row n zeros). agg[d] = dinv[d]*sum q[src] (fp32 acc,
// bf16 for MFMA A). One 32-row tile per block (grid = ntiles = 12.2 blocks/CU,
// 8 resident -> max occupancy w/ backfill). 4 waves: wave w -> C rows
// (w&1)*16..+16, cols (w>>1)*64..+64 (16 mfma_f32_16x16x32_bf16).
// Gather: 16 concurrent 8B loads/lane. Epilogue via LDS Cs (coalesced 8B).
__global__ __launch_bounds__(256, 8) void k_fused(
        const u32* __restrict__ hin, const int* __restrict__ offs,
        const int* __restrict__ srcS, const float* __restrict__ dinv,
        const u32* __restrict__ wt, const float* __restrict__ bias,
        u32* __restrict__ out, int n, int ntiles, int last) {
    __shared__ __align__(16) u32 buf[TROWS * CRS];   // 16.9 KB union As/Cs
    float* Cs = (float*)buf;
    int tid = threadIdx.x;
    int grp = tid >> 5;          // 0..7 (gather/epilogue groups)
    int lane32 = tid & 31;
    int c4 = lane32 << 2;        // channel offset (4 ch/lane)
    int cu = lane32 << 1;        // uint offset within bf16 row
    int wv = tid >> 6;           // wave 0..3 (MFMA phase)
    int lane = tid & 63;
    int m0 = (wv & 1) * 16;      // M-tile base row
    int nh = wv >> 1;            // N-half (cols nh*64..+64)
    int mrow = lane & 15, quad = lane >> 4;

    float4 bv = *(const float4*)(bias + c4);   // constant across tiles

    for (int tile = blockIdx.x; tile < ntiles; tile += gridDim.x) {
        int row0 = tile * TROWS;

        // ---- gather/sum phase (fp32 acc, bf16 As) ----
        #pragma unroll
        for (int i = 0; i < 4; ++i) {
            int r = grp * 4 + i;
            int node = row0 + r;
            float4 acc = make_float4(0.f, 0.f, 0.f, 0.f);
            if (node < n) {
                int b = offs[node], e = offs[node + 1];
                int j = b;
                for (; j + 16 <= e; j += 16) {
                    int4 sa = *(const int4*)(srcS + j);
                    int4 sb = *(const int4*)(srcS + j + 4);
                    int4 sc = *(const int4*)(srcS + j + 8);
                    int4 sd = *(const int4*)(srcS + j + 12);
                    b4 q0 = *(const b4*)(hin + (size_t)sa.x * NU + cu);
                    b4 q1 = *(const b4*)(hin + (size_t)sa.y * NU + cu);
                    b4 q2 = *(const b4*)(hin + (size_t)sa.z * NU + cu);
                    b4 q3 = *(const b4*)(hin + (size_t)sa.w * NU + cu);
                    b4 q4 = *(const b4*)(hin + (size_t)sb.x * NU + cu);
                    b4 q5 = *(const b4*)(hin + (size_t)sb.y * NU + cu);
                    b4 q6 = *(const b4*)(hin + (size_t)sb.z * NU + cu);
                    b4 q7 = *(const b4*)(hin + (size_t)sb.w * NU + cu);
                    b4 q8 = *(const b4*)(hin + (size_t)sc.x * NU + cu);
                    b4 q9 = *(const b4*)(hin + (size_t)sc.y * NU + cu);
                    b4 qa = *(const b4*)(hin + (size_t)sc.z * NU + cu);
                    b4 qb = *(const b4*)(hin + (size_t)sc.w * NU + cu);
                    b4 qc = *(const b4*)(hin + (size_t)sd.x * NU + cu);
                    b4 qd = *(const b4*)(hin + (size_t)sd.y * NU + cu);
                    b4 qe = *(const b4*)(hin + (size_t)sd.z * NU + cu);
                    b4 qf = *(const b4*)(hin + (size_t)sd.w * NU + cu);
                    acc.x += (((bflo(q0.x) + bflo(q1.x)) + (bflo(q2.x) + bflo(q3.x)))
                            + ((bflo(q4.x) + bflo(q5.x)) + (bflo(q6.x) + bflo(q7.x))))
                           + (((bflo(q8.x) + bflo(q9.x)) + (bflo(qa.x) + bflo(qb.x)))
                            + ((bflo(qc.x) + bflo(qd.x)) + (bflo(qe.x) + bflo(qf.x))));
                    acc.y += (((bfhi(q0.x) + bfhi(q1.x)) + (bfhi(q2.x) + bfhi(q3.x)))
                            + ((bfhi(q4.x) + bfhi(q5.x)) + (bfhi(q6.x) + bfhi(q7.x))))
                           + (((bfhi(q8.x) + bfhi(q9.x)) + (bfhi(qa.x) + bfhi(qb.x)))
                            + ((bfhi(qc.x) + bfhi(qd.x)) + (bfhi(qe.x) + bfhi(qf.x))));
                    acc.z += (((bflo(q0.y) + bflo(q1.y)) + (bflo(q2.y) + bflo(q3.y)))
                            + ((bflo(q4.y) + bflo(q5.y)) + (bflo(q6.y) + bflo(q7.y))))
                           + (((bflo(q8.y) + bflo(q9.y)) + (bflo(qa.y) + bflo(qb.y)))
                            + ((bflo(qc.y) + bflo(qd.y)) + (bflo(qe.y) + bflo(qf.y))));
                    acc.w += (((bfhi(q0.y) + bfhi(q1.y)) + (bfhi(q2.y) + bfhi(q3.y)))
                            + ((bfhi(q4.y) + bfhi(q5.y)) + (bfhi(q6.y) + bfhi(q7.y))))
                           + (((bfhi(q8.y) + bfhi(q9.y)) + (bfhi(qa.y) + bfhi(qb.y)))
                            + ((bfhi(qc.y) + bfhi(qd.y)) + (bfhi(qe.y) + bfhi(qf.y))));
                }
                for (; j + 8 <= e; j += 8) {
                    int4 sa = *(const int4*)(srcS + j);
                    int4 sb = *(const int4*)(srcS + j + 4);
                    b4 q0 = *(const b4*)(hin + (size_t)sa.x * NU + cu);
                    b4 q1 = *(const b4*)(hin + (size_t)sa.y * NU + cu);
                    b4 q2 = *(const b4*)(hin + (size_t)sa.z * NU + cu);
                    b4 q3 = *(const b4*)(hin + (size_t)sa.w * NU + cu);
                    b4 q4 = *(const b4*)(hin + (size_t)sb.x * NU + cu);
                    b4 q5 = *(const b4*)(hin + (size_t)sb.y * NU + cu);
                    b4 q6 = *(const b4*)(hin + (size_t)sb.z * NU + cu);
                    b4 q7 = *(const b4*)(hin + (size_t)sb.w * NU + cu);
                    acc.x += ((bflo(q0.x) + bflo(q1.x)) + (bflo(q2.x) + bflo(q3.x)))
                           + ((bflo(q4.x) + bflo(q5.x)) + (bflo(q6.x) + bflo(q7.x)));
                    acc.y += ((bfhi(q0.x) + bfhi(q1.x)) + (bfhi(q2.x) + bfhi(q3.x)))
                           + ((bfhi(q4.x) + bfhi(q5.x)) + (bfhi(q6.x) + bfhi(q7.x)));
                    acc.z += ((bflo(q0.y) + bflo(q1.y)) + (bflo(q2.y) + bflo(q3.y)))
                           + ((bflo(q4.y) + bflo(q5.y)) + (bflo(q6.y) + bflo(q7.y)));
                    acc.w += ((bfhi(q0.y) + bfhi(q1.y)) + (bfhi(q2.y) + bfhi(q3.y)))
                           + ((bfhi(q4.y) + bfhi(q5.y)) + (bfhi(q6.y) + bfhi(q7.y)));
                }
                if (j < e) {                 // exactly 4 remain
                    int4 sa = *(const int4*)(srcS + j);
                    b4 q0 = *(const b4*)(hin + (size_t)sa.x * NU + cu);
                    b4 q1 = *(const b4*)(hin + (size_t)sa.y * NU + cu);
                    b4 q2 = *(const b4*)(hin + (size_t)sa.z * NU + cu);
                    b4 q3 = *(const b4*)(hin + (size_t)sa.w * NU + cu);
                    acc.x += (bflo(q0.x) + bflo(q1.x)) + (bflo(q2.x) + bflo(q3.x));
                    acc.y += (bfhi(q0.x) + bfhi(q1.x)) + (bfhi(q2.x) + bfhi(q3.x));
                    acc.z += (bflo(q0.y) + bflo(q1.y)) + (bflo(q2.y) + bflo(q3.y));
                    acc.w += (bfhi(q0.y) + bfhi(q1.y)) + (bfhi(q2.y) + bfhi(q3.y));
                }
                float dn = dinv[node];
                acc.x *= dn; acc.y *= dn; acc.z *= dn; acc.w *= dn;
            }
            b4 o; o.x = pack2(acc.x, acc.y); o.y = pack2(acc.z, acc.w);
            *(b4*)(buf + r * ARS + cu) = o;
        }
        __syncthreads();

        // ---- MFMA GEMM phase ----
        f32x4 a0 = {0.f, 0.f, 0.f, 0.f}, a1 = a0, a2 = a0, a3 = a0;
        #pragma unroll
        for (int ks = 0; ks < 4; ++ks) {
            bf16x8 a = *(const bf16x8*)(buf + (m0 + mrow) * ARS + ks * 16 + quad * 4);
            const u32* wb = wt + (((nh * 4) * 4 + ks) * 64 + lane) * 4;
            bf16x8 b0 = *(const bf16x8*)(wb);
            bf16x8 b1 = *(const bf16x8*)(wb + 1024);   // nt+1 -> +256 uint4
            bf16x8 b2 = *(const bf16x8*)(wb + 2048);
            bf16x8 b3 = *(const bf16x8*)(wb + 3072);
            a0 = __builtin_amdgcn_mfma_f32_16x16x32_bf16(a, b0, a0, 0, 0, 0);
            a1 = __builtin_amdgcn_mfma_f32_16x16x32_bf16(a, b1, a1, 0, 0, 0);
            a2 = __builtin_amdgcn_mfma_f32_16x16x32_bf16(a, b2, a2, 0, 0, 0);
            a3 = __builtin_amdgcn_mfma_f32_16x16x32_bf16(a, b3, a3, 0, 0, 0);
        }
        __syncthreads();   // all As reads done before Cs overwrites the union

        // C frags -> LDS (col = lane&15, row = quad*4+reg)
        #pragma unroll
        for (int nt = 0; nt < 4; ++nt) {
            f32x4 av = nt == 0 ? a0 : nt == 1 ? a1 : nt == 2 ? a2 : a3;
            int col = (nh * 4 + nt) * 16 + mrow;
            #pragma unroll
            for (int rg = 0; rg < 4; ++rg)
                Cs[(m0 + quad * 4 + rg) * CRS + col] = av[rg];
        }
        __syncthreads();

        // ---- epilogue: bias + ReLU (+ dinv rescale), pack bf16, coalesced store ----
        #pragma unroll
        for (int j = 0; j < 4; ++j) {
            int r = grp * 4 + j;
            int gr = row0 + r;
            if (gr <= n) {
                b4 o; o.x = 0u; o.y = 0u;
                if (gr < n) {
                    float4 v = *(const float4*)(Cs + r * CRS + c4);
                    float sc = last ? 1.0f : dinv[gr];
                    float ox = fmaxf(v.x + bv.x, 0.f) * sc;
                    float oy = fmaxf(v.y + bv.y, 0.f) * sc;
                    float oz = fmaxf(v.z + bv.z, 0.f) * sc;
                    float ow = fmaxf(v.w + bv.w, 0.f) * sc;
                    o.x = pack2(ox, oy);
                    o.y = pack2(oz, ow);
                }
                *(b4*)(out + (size_t)gr * NU + cu) = o;   // gr==n keeps sentinel 0
            }
        }
        __syncthreads();   // buf reused as As next tile
    }
}

// ---------- fused pool + head (batch sorted -> contiguous ranges; bounds inline) ----------

__global__ __launch_bounds__(256) void k_poolfinal(const u32* __restrict__ h,
        const int* __restrict__ batch, const float* __restrict__ linW,
        const float* __restrict__ linb, float* __restrict__ outp, int N) {
    int g = blockIdx.x;
    int tid = threadIdx.x;
    __shared__ int sb[2];
    if (tid < 2) {                       // lower_bound(batch, g+tid)
        int target = g + tid;
        int lo = 0, hi = N;
        while (lo < hi) {
            int mid = (lo + hi) >> 1;
            if (batch[mid] < target) lo = mid + 1; else hi = mid;
        }
        sb[tid] = lo;
    }
    __syncthreads();
    int b = sb[0], e = sb[1];

    int grp = tid >> 5, lane = tid & 31;
    int c4 = lane << 2, cu = lane << 1;
    float4 acc = make_float4(0.f, 0.f, 0.f, 0.f);
    for (int i = b + grp; i < e; i += 8) {
        b4 v = *(const b4*)(h + (size_t)i * NU + cu);
        acc.x += bflo(v.x); acc.y += bfhi(v.x);
        acc.z += bflo(v.y); acc.w += bfhi(v.y);
    }
    __shared__ float red[8][NF];
    *(float4*)(&red[grp][c4]) = acc;
    __syncthreads();

    float v0 = 0.f, v1 = 0.f;
    if (tid < NF) {
        float s = 0.f;
        #pragma unroll
        for (int gg = 0; gg < 8; ++gg) s += red[gg][tid];
        v0 = s * linW[tid * 2 + 0];
        v1 = s * linW[tid * 2 + 1];
    }
    #pragma unroll
    for (int d = 32; d > 0; d >>= 1) {
        v0 += __shfl_down(v0, d);
        v1 += __shfl_down(v1, d);
    }
    __shared__ float sv[8];
    if ((tid & 63) == 0) { sv[(tid >> 6) * 2] = v0; sv[(tid >> 6) * 2 + 1] = v1; }
    __syncthreads();
    if (tid == 0) {
        float inv = 1.0f / fmaxf((float)(e - b), 1.0f);
        outp[g * 2 + 0] = (sv[0] + sv[2]) * inv + linb[0];
        outp[g * 2 + 1] = (sv[1] + sv[3]) * inv + linb[1];
    }
}

// ---------- launcher ----------

extern "C" void kernel_launch(void* const* d_in, const int* in_sizes, int n_in,
                              void* d_out, int out_size, void* d_ws, size_t ws_size,
                              hipStream_t stream) {
    const float* x     = (const float*)d_in[0];
    const int*   ei    = (const int*)d_in[1];
    const int*   batch = (const int*)d_in[2];
    const float* Wl[4] = {(const float*)d_in[3], (const float*)d_in[5],
                          (const float*)d_in[7], (const float*)d_in[9]};
    const float* bl[4] = {(const float*)d_in[4], (const float*)d_in[6],
                          (const float*)d_in[8], (const float*)d_in[10]};
    const float* linW  = (const float*)d_in[11];
    const float* linb  = (const float*)d_in[12];
    float* out = (float*)d_out;

    const int N  = in_sizes[2];
    const int E  = in_sizes[1] / 2;
    const int G  = out_size / 2;

    // carve workspace (256B-aligned slices)
    char* p = (char*)d_ws;
    auto carve = [&](size_t bytes) -> char* {
        char* r = p;
        p += (bytes + 255) & ~(size_t)255;
        return r;
    };
    int*   cnt    = (int*)  carve((size_t)N * 4);
    float* dinv   = (float*)carve((size_t)N * 4);
    int*   offs   = (int*)  carve((size_t)(N + 1) * 4);
    int*   cursor = (int*)  carve((size_t)(N + 1) * 4);
    int*   bsum   = (int*)  carve(512 * 4);
    u32*   wt     = (u32*)  carve(4 * 2048 * 16);              // bf16 W fragments
    int*   srcS   = (int*)  carve((size_t)(E + 4 * (size_t)N) * 4);   // padded CSR
    u32*   bufA   = (u32*)  carve((size_t)(N + 1) * NU * 4);   // bf16 ping (row N = 0)
    u32*   bufB   = (u32*)  carve((size_t)(N + 1) * NU * 4);   // bf16 pong (row N = 0)

    (void)hipMemsetAsync(cnt, 0, (size_t)N * 4, stream);
    k_deg<<<(E + 255) / 256, 256, 0, stream>>>(ei, cnt, E);

    int nb = (N + 1 + 255) / 256;   // covers items 0..N (item N has count 0)
    k_scan1<<<nb, 256, 0, stream>>>(cnt, dinv, offs, bsum, N);
    k_scan2<<<1, 512, 0, stream>>>(bsum, nb);
    k_scan3<<<nb, 256, 0, stream>>>(offs, bsum, cursor, N);

    int totalu4 = (N + 1) * (NU / 4);
    int prepT = totalu4 > E + N ? totalu4 : E + N;
    k_prep<<<(prepT + 255) / 256, 256, 0, stream>>>(ei, x, dinv, cnt, offs, cursor,
                                                    srcS, bufA,
                                                    Wl[0], Wl[1], Wl[2], Wl[3], wt,
                                                    E, N);

    int ntiles = (N + 1 + TROWS - 1) / TROWS;    // 3126 blocks = 12.2/CU, 8 resident
    const u32* hin = bufA;
    u32* hout = bufB;
    for (int l = 0; l < 4; ++l) {
        k_fused<<<ntiles, 256, 0, stream>>>(hin, offs, srcS, dinv, wt + l * 8192,
                                            bl[l], hout, N, ntiles, l == 3);
        hin = hout;
        hout = (hout == bufA) ? bufB : bufA;
    }

    k_poolfinal<<<G, 256, 0, stream>>>(hin, batch, linW, linb, out, N);
}

// Round 13
// 738.979 us; speedup vs baseline: 1.1476x; 1.1476x over previous
//
#include <hip/hip_runtime.h>
#include <math.h>

#define NF 128      // feature/hidden dim (F == H == 128)
#define NU 64       // uints per bf16 row (NF/2)
#define TROWS 32    // fused-kernel tile rows
#define ARS 68      // As row stride in u32 (64 + 4 pad)
#define CRS 132     // Cs row stride in floats (128 + 4 pad)

typedef unsigned int  u32;
typedef unsigned short u16;
typedef u32 b4 __attribute__((ext_vector_type(2)));     // 4 bf16 (8B)
typedef short bf16x8 __attribute__((ext_vector_type(8)));  // MFMA A/B frag (16B)
typedef float f32x4 __attribute__((ext_vector_type(4)));   // MFMA C/D frag

__device__ inline u16 f2bf(float f) {               // RNE float->bf16
    u32 u = __float_as_uint(f);
    return (u16)((u + 0x7fffu + ((u >> 16) & 1u)) >> 16);
}
__device__ inline u32 pack2(float a, float b) {     // ch2k=lo, ch2k+1=hi
    return (u32)f2bf(a) | ((u32)f2bf(b) << 16);
}
__device__ inline float bflo(u32 u) { return __uint_as_float(u << 16); }
__device__ inline float bfhi(u32 u) { return __uint_as_float(u & 0xffff0000u); }

// ---------- setup kernels ----------

__global__ void k_deg(const int* __restrict__ ei, int* cnt, int E) {
    int e = blockIdx.x * blockDim.x + threadIdx.x;
    if (e < E) atomicAdd(&cnt[ei[E + e]], 1);   // dst row; cnt = deg w/o self-loop
}

// Exclusive scan over PADDED counts vpad = roundup(cnt+1, 4); item n has v=0 so
// offs[n] lands automatically. Also emits dinv = rsqrt(real deg).
__global__ void k_scan1(const int* __restrict__ cnt, float* dinv,
                        int* offs, int* bsum, int n) {
    __shared__ int s[256];
    int t = threadIdx.x;
    int i = blockIdx.x * 256 + t;
    int v = 0;
    if (i < n) {
        int real = cnt[i] + 1;          // +1 self-loop
        dinv[i] = 1.0f / sqrtf((float)real);
        v = (real + 3) & ~3;            // pad row to multiple of 4
    }
    s[t] = v;
    for (int d = 1; d < 256; d <<= 1) {
        __syncthreads();
        int add = (t >= d) ? s[t - d] : 0;
        __syncthreads();
        s[t] += add;
    }
    __syncthreads();
    if (i <= n) offs[i] = s[t] - v;          // exclusive
    if (t == 255) bsum[blockIdx.x] = s[255]; // block total
}

__global__ void k_scan2(int* bsum, int nb) {
    __shared__ int s[512];
    int t = threadIdx.x;
    int v = (t < nb) ? bsum[t] : 0;
    s[t] = v;
    for (int d = 1; d < 512; d <<= 1) {
        __syncthreads();
        int add = (t >= d) ? s[t - d] : 0;
        __syncthreads();
        s[t] += add;
    }
    __syncthreads();
    if (t < nb) bsum[t] = s[t] - v;         // exclusive
}

__global__ void k_scan3(int* offs, const int* __restrict__ bsum, int* cursor, int n) {
    int i = blockIdx.x * 256 + threadIdx.x;
    if (i <= n) {
        int o = offs[i] + bsum[blockIdx.x];
        offs[i] = o;
        cursor[i] = o;
    }
}

// One prep kernel:
//  (a) q0[row] = bf16(dinv[row] * x[row])  (row n -> zeros; sentinel row)
//  (b) scatter real edges into padded dst-sorted CSR via atomic cursor,
//      self-loop + sentinel padding at row end
//  (c) t < 8192: pre-swizzled bf16 B-fragments of the 4 weight matrices.
__global__ void k_prep(const int* __restrict__ ei, const float* __restrict__ x,
                       const float* __restrict__ dinv, const int* __restrict__ cnt,
                       const int* __restrict__ offs, int* cursor, int* srcS,
                       u32* __restrict__ q,
                       const float* __restrict__ W0, const float* __restrict__ W1,
                       const float* __restrict__ W2, const float* __restrict__ W3,
                       u32* __restrict__ wt, int E, int n) {
    int t = blockIdx.x * blockDim.x + threadIdx.x;
    int totalu4 = (n + 1) * (NU / 4);     // 16 uint4 per row
    if (t < totalu4) {
        int row = t >> 4;
        uint4 o = make_uint4(0, 0, 0, 0);
        if (row < n) {
            int cbase = (t & 15) << 3;    // 8 channels per uint4
            const float* xr = x + (size_t)row * NF + cbase;
            float4 f0 = *(const float4*)(xr);
            float4 f1 = *(const float4*)(xr + 4);
            float d = dinv[row];
            o.x = pack2(f0.x * d, f0.y * d);
            o.y = pack2(f0.z * d, f0.w * d);
            o.z = pack2(f1.x * d, f1.y * d);
            o.w = pack2(f1.z * d, f1.w * d);
        }
        ((uint4*)q)[t] = o;
    }
    if (t < E) {
        int s = ei[t], d = ei[E + t];
        int p = atomicAdd(&cursor[d], 1);
        srcS[p] = s;
    } else if (t < E + n) {
        int i = t - E;
        int base = offs[i] + cnt[i];      // after the cnt[i] real edges
        srcS[base] = i;                   // self-loop
        int end = offs[i + 1];
        for (int k = base + 1; k < end; ++k) srcS[k] = n;   // sentinel padding
    }
    if (t < 4 * 2048) {
        int layer = t >> 11;
        int rem = t & 2047;               // = (nt*4+ks)*64 + lane
        int lane = rem & 63;
        int ks = (rem >> 6) & 3;
        int nt = rem >> 8;
        const float* W = layer == 0 ? W0 : layer == 1 ? W1 : layer == 2 ? W2 : W3;
        int nn = nt * 16 + (lane & 15);
        int k0 = ks * 32 + (lane >> 4) * 8;
        uint4 o;
        o.x = pack2(W[(k0 + 0) * NF + nn], W[(k0 + 1) * NF + nn]);
        o.y = pack2(W[(k0 + 2) * NF + nn], W[(k0 + 3) * NF + nn]);
        o.z = pack2(W[(k0 + 4) * NF + nn], W[(k0 + 5) * NF + nn]);
        o.w = pack2(W[(k0 + 6) * NF + nn], W[(k0 + 7) * NF + nn]);
        ((uint4*)wt)[t] = o;
    }
}

// ---------- fused layer: bf16 gather-sum -> bf16 LDS tile -> MFMA GEMM -> epilogue ----------
// Round-10 config (best measured): grid = ntiles/2 (2 tiles/block), x8 gather
// unroll, (256,8), LDS-C epilogue with coalesced 8B stores.
// Bias+ReLU applied at C-fragment->Cs store. Layers 0-2: out = bf16(dinv*h).
// Last layer: NO h write — per-tile segment-sum of fp32 Cs rows by graph id
// (batch sorted -> <=2 segments/tile) atomicAdd'ed into pooled[G][NF].
__global__ __launch_bounds__(256, 8) void k_fused(
        const u32* __restrict__ hin, const int* __restrict__ offs,
        const int* __restrict__ srcS, const float* __restrict__ dinv,
        const u32* __restrict__ wt, const float* __restrict__ bias,
        u32* __restrict__ out, const int* __restrict__ batch,
        float* __restrict__ pooled, int n, int ntiles, int last) {
    __shared__ __align__(16) u32 buf[TROWS * CRS];   // 16.9 KB union As/Cs
    __shared__ int sbatch[TROWS];
    float* Cs = (float*)buf;
    int tid = threadIdx.x;
    int grp = tid >> 5;          // 0..7 (gather/epilogue groups)
    int lane32 = tid & 31;
    int c4 = lane32 << 2;        // channel offset (4 ch/lane)
    int cu = lane32 << 1;        // uint offset within bf16 row
    int wv = tid >> 6;           // wave 0..3 (MFMA phase)
    int lane = tid & 63;
    int m0 = (wv & 1) * 16;      // M-tile base row
    int nh = wv >> 1;            // N-half (cols nh*64..+64)
    int mrow = lane & 15, quad = lane >> 4;

    float bcol[4];               // bias for this lane's 4 column tiles
    #pragma unroll
    for (int nt = 0; nt < 4; ++nt) bcol[nt] = bias[(nh * 4 + nt) * 16 + mrow];

    for (int tile = blockIdx.x; tile < ntiles; tile += gridDim.x) {
        int row0 = tile * TROWS;

        // ---- gather/sum phase (fp32 acc, bf16 As) ----
        #pragma unroll
        for (int i = 0; i < 4; ++i) {
            int r = grp * 4 + i;
            int node = row0 + r;
            float4 acc = make_float4(0.f, 0.f, 0.f, 0.f);
            if (node < n) {
                int b = offs[node], e = offs[node + 1];
                int j = b;
                for (; j + 8 <= e; j += 8) {
                    int4 sa = *(const int4*)(srcS + j);
                    int4 sb = *(const int4*)(srcS + j + 4);
                    b4 q0 = *(const b4*)(hin + (size_t)sa.x * NU + cu);
                    b4 q1 = *(const b4*)(hin + (size_t)sa.y * NU + cu);
                    b4 q2 = *(const b4*)(hin + (size_t)sa.z * NU + cu);
                    b4 q3 = *(const b4*)(hin + (size_t)sa.w * NU + cu);
                    b4 q4 = *(const b4*)(hin + (size_t)sb.x * NU + cu);
                    b4 q5 = *(const b4*)(hin + (size_t)sb.y * NU + cu);
                    b4 q6 = *(const b4*)(hin + (size_t)sb.z * NU + cu);
                    b4 q7 = *(const b4*)(hin + (size_t)sb.w * NU + cu);
                    acc.x += ((bflo(q0.x) + bflo(q1.x)) + (bflo(q2.x) + bflo(q3.x)))
                           + ((bflo(q4.x) + bflo(q5.x)) + (bflo(q6.x) + bflo(q7.x)));
                    acc.y += ((bfhi(q0.x) + bfhi(q1.x)) + (bfhi(q2.x) + bfhi(q3.x)))
                           + ((bfhi(q4.x) + bfhi(q5.x)) + (bfhi(q6.x) + bfhi(q7.x)));
                    acc.z += ((bflo(q0.y) + bflo(q1.y)) + (bflo(q2.y) + bflo(q3.y)))
                           + ((bflo(q4.y) + bflo(q5.y)) + (bflo(q6.y) + bflo(q7.y)));
                    acc.w += ((bfhi(q0.y) + bfhi(q1.y)) + (bfhi(q2.y) + bfhi(q3.y)))
                           + ((bfhi(q4.y) + bfhi(q5.y)) + (bfhi(q6.y) + bfhi(q7.y)));
                }
                if (j < e) {                 // exactly 4 remain (count % 8 == 4)
                    int4 sa = *(const int4*)(srcS + j);
                    b4 q0 = *(const b4*)(hin + (size_t)sa.x * NU + cu);
                    b4 q1 = *(const b4*)(hin + (size_t)sa.y * NU + cu);
                    b4 q2 = *(const b4*)(hin + (size_t)sa.z * NU + cu);
                    b4 q3 = *(const b4*)(hin + (size_t)sa.w * NU + cu);
                    acc.x += (bflo(q0.x) + bflo(q1.x)) + (bflo(q2.x) + bflo(q3.x));
                    acc.y += (bfhi(q0.x) + bfhi(q1.x)) + (bfhi(q2.x) + bfhi(q3.x));
                    acc.z += (bflo(q0.y) + bflo(q1.y)) + (bflo(q2.y) + bflo(q3.y));
                    acc.w += (bfhi(q0.y) + bfhi(q1.y)) + (bfhi(q2.y) + bfhi(q3.y));
                }
                float dn = dinv[node];
                acc.x *= dn; acc.y *= dn; acc.z *= dn; acc.w *= dn;
            }
            b4 o; o.x = pack2(acc.x, acc.y); o.y = pack2(acc.z, acc.w);
            *(b4*)(buf + r * ARS + cu) = o;
        }
        if (last && tid < TROWS) {
            int gr = row0 + tid;
            sbatch[tid] = (gr < n) ? batch[gr] : -1;
        }
        __syncthreads();

        // ---- MFMA GEMM phase ----
        f32x4 a0 = {0.f, 0.f, 0.f, 0.f}, a1 = a0, a2 = a0, a3 = a0;
        #pragma unroll
        for (int ks = 0; ks < 4; ++ks) {
            bf16x8 a = *(const bf16x8*)(buf + (m0 + mrow) * ARS + ks * 16 + quad * 4);
            const u32* wb = wt + (((nh * 4) * 4 + ks) * 64 + lane) * 4;
            bf16x8 b0 = *(const bf16x8*)(wb);
            bf16x8 b1 = *(const bf16x8*)(wb + 1024);   // nt+1 -> +256 uint4
            bf16x8 b2 = *(const bf16x8*)(wb + 2048);
            bf16x8 b3 = *(const bf16x8*)(wb + 3072);
            a0 = __builtin_amdgcn_mfma_f32_16x16x32_bf16(a, b0, a0, 0, 0, 0);
            a1 = __builtin_amdgcn_mfma_f32_16x16x32_bf16(a, b1, a1, 0, 0, 0);
            a2 = __builtin_amdgcn_mfma_f32_16x16x32_bf16(a, b2, a2, 0, 0, 0);
            a3 = __builtin_amdgcn_mfma_f32_16x16x32_bf16(a, b3, a3, 0, 0, 0);
        }
        __syncthreads();   // all As reads done before Cs overwrites the union

        // C frags -> LDS with bias+ReLU (col = lane&15, row = quad*4+reg)
        #pragma unroll
        for (int nt = 0; nt < 4; ++nt) {
            f32x4 av = nt == 0 ? a0 : nt == 1 ? a1 : nt == 2 ? a2 : a3;
            int col = (nh * 4 + nt) * 16 + mrow;
            float bb = bcol[nt];
            #pragma unroll
            for (int rg = 0; rg < 4; ++rg)
                Cs[(m0 + quad * 4 + rg) * CRS + col] = fmaxf(av[rg] + bb, 0.f);
        }
        __syncthreads();

        if (!last) {
            // ---- epilogue: dinv rescale, pack bf16, coalesced 8B store ----
            #pragma unroll
            for (int j = 0; j < 4; ++j) {
                int r = grp * 4 + j;
                int gr = row0 + r;
                if (gr <= n) {
                    b4 o; o.x = 0u; o.y = 0u;
                    if (gr < n) {
                        float4 v = *(const float4*)(Cs + r * CRS + c4);
                        float sc = dinv[gr];
                        o.x = pack2(v.x * sc, v.y * sc);
                        o.y = pack2(v.z * sc, v.w * sc);
                    }
                    *(b4*)(out + (size_t)gr * NU + cu) = o;   // gr==n keeps sentinel 0
                }
            }
        } else {
            // ---- pooling epilogue: segment-sum rows by graph id, atomicAdd ----
            int c = tid & 127;           // channel
            int half = tid >> 7;         // rows half*16 .. half*16+15
            float accs = 0.f;
            int curg = -1;
            #pragma unroll 4
            for (int r = half * 16; r < half * 16 + 16; ++r) {
                int g = sbatch[r];
                if (g != curg) {
                    if (curg >= 0) atomicAdd(&pooled[(size_t)curg * NF + c], accs);
                    curg = g; accs = 0.f;
                }
                if (g >= 0) accs += Cs[r * CRS + c];
            }
            if (curg >= 0) atomicAdd(&pooled[(size_t)curg * NF + c], accs);
        }
        __syncthreads();   // buf/sbatch reused next tile
    }
}

// ---------- head: out[g][j] = dot(pooled[g], linW[:,j]) / count[g] + linb[j] ----------

__global__ __launch_bounds__(256) void k_head(const float* __restrict__ pooled,
        const int* __restrict__ batch, const float* __restrict__ linW,
        const float* __restrict__ linb, float* __restrict__ outp, int N, int G2) {
    int t = blockIdx.x * blockDim.x + threadIdx.x;
    if (t >= G2) return;
    int g = t >> 1, j = t & 1;
    int b, e;
    {   // lower_bound(batch, g) and lower_bound(batch, g+1)
        int lo = 0, hi = N;
        while (lo < hi) { int m = (lo + hi) >> 1; if (batch[m] < g) lo = m + 1; else hi = m; }
        b = lo;
        hi = N;
        while (lo < hi) { int m = (lo + hi) >> 1; if (batch[m] < g + 1) lo = m + 1; else hi = m; }
        e = lo;
    }
    const float* pr = pooled + (size_t)g * NF;
    float s = 0.f;
    #pragma unroll 8
    for (int c = 0; c < NF; ++c) s += pr[c] * linW[c * 2 + j];
    outp[t] = s / fmaxf((float)(e - b), 1.0f) + linb[j];
}

// ---------- launcher ----------

extern "C" void kernel_launch(void* const* d_in, const int* in_sizes, int n_in,
                              void* d_out, int out_size, void* d_ws, size_t ws_size,
                              hipStream_t stream) {
    const float* x     = (const float*)d_in[0];
    const int*   ei    = (const int*)d_in[1];
    const int*   batch = (const int*)d_in[2];
    const float* Wl[4] = {(const float*)d_in[3], (const float*)d_in[5],
                          (const float*)d_in[7], (const float*)d_in[9]};
    const float* bl[4] = {(const float*)d_in[4], (const float*)d_in[6],
                          (const float*)d_in[8], (const float*)d_in[10]};
    const float* linW  = (const float*)d_in[11];
    const float* linb  = (const float*)d_in[12];
    float* out = (float*)d_out;

    const int N  = in_sizes[2];
    const int E  = in_sizes[1] / 2;
    const int G  = out_size / 2;

    // carve workspace (256B-aligned slices)
    char* p = (char*)d_ws;
    auto carve = [&](size_t bytes) -> char* {
        char* r = p;
        p += (bytes + 255) & ~(size_t)255;
        return r;
    };
    int*   cnt    = (int*)  carve((size_t)N * 4);
    float* dinv   = (float*)carve((size_t)N * 4);
    int*   offs   = (int*)  carve((size_t)(N + 1) * 4);
    int*   cursor = (int*)  carve((size_t)(N + 1) * 4);
    int*   bsum   = (int*)  carve(512 * 4);
    u32*   wt     = (u32*)  carve(4 * 2048 * 16);              // bf16 W fragments
    float* pooled = (float*)carve((size_t)G * NF * 4);         // fp32 pool accum
    int*   srcS   = (int*)  carve((size_t)(E + 4 * (size_t)N) * 4);   // padded CSR
    u32*   bufA   = (u32*)  carve((size_t)(N + 1) * NU * 4);   // bf16 ping (row N = 0)
    u32*   bufB   = (u32*)  carve((size_t)(N + 1) * NU * 4);   // bf16 pong (row N = 0)

    (void)hipMemsetAsync(cnt, 0, (size_t)N * 4, stream);
    (void)hipMemsetAsync(pooled, 0, (size_t)G * NF * 4, stream);
    k_deg<<<(E + 255) / 256, 256, 0, stream>>>(ei, cnt, E);

    int nb = (N + 1 + 255) / 256;   // covers items 0..N (item N has count 0)
    k_scan1<<<nb, 256, 0, stream>>>(cnt, dinv, offs, bsum, N);
    k_scan2<<<1, 512, 0, stream>>>(bsum, nb);
    k_scan3<<<nb, 256, 0, stream>>>(offs, bsum, cursor, N);

    int totalu4 = (N + 1) * (NU / 4);
    int prepT = totalu4 > E + N ? totalu4 : E + N;
    k_prep<<<(prepT + 255) / 256, 256, 0, stream>>>(ei, x, dinv, cnt, offs, cursor,
                                                    srcS, bufA,
                                                    Wl[0], Wl[1], Wl[2], Wl[3], wt,
                                                    E, N);

    int ntiles = (N + 1 + TROWS - 1) / TROWS;
    int k = (ntiles + 2047) / 2048;                 // tiles per block
    int ngrid = (ntiles + k - 1) / k;               // 1563 for N=100000 (2 tiles ea)
    const u32* hin = bufA;
    u32* hout = bufB;
    for (int l = 0; l < 4; ++l) {
        k_fused<<<ngrid, 256, 0, stream>>>(hin, offs, srcS, dinv, wt + l * 8192,
                                           bl[l], hout, batch, pooled,
                                           N, ntiles, l == 3);
        hin = hout;
        hout = (hout == bufA) ? bufB : bufA;
    }

    k_head<<<(2 * G + 255) / 256, 256, 0, stream>>>(pooled, batch, linW, linb,
                                                    out, N, 2 * G);
}